// Round 1
// baseline (545.184 us; speedup 1.0000x reference)
//
#include <hip/hip_runtime.h>
#include <hip/hip_bf16.h>

#define D_MODEL 512
#define NH      8
#define DK      64
#define SEQ     2048
#define BATCH   4
#define WINDOW  256
#define ROWS    (BATCH*SEQ)   // 8192

// ---------------------------------------------------------------------------
// K1: projection GEMM  X[8192x512](f32) @ W[512x512](f32) -> out bf16 [B,H,L,64]
// ---------------------------------------------------------------------------
__global__ __launch_bounds__(256)
void proj_gemm(const float* __restrict__ X, const float* __restrict__ W,
               __hip_bfloat16* __restrict__ out) {
    __shared__ float As[16][65];   // [k][m]
    __shared__ float Bs[16][65];   // [k][n]

    const int tid = threadIdx.x;
    const int tx = tid & 15, ty = tid >> 4;
    const int row0 = blockIdx.x * 64;
    const int col0 = blockIdx.y * 64;

    float acc[4][4] = {};

    for (int k0 = 0; k0 < D_MODEL; k0 += 16) {
        {   // A tile: 64 rows x 16 k
            const int r = tid >> 4, k = tid & 15;
            #pragma unroll
            for (int i = 0; i < 4; ++i)
                As[k][r + i*16] = X[(size_t)(row0 + r + i*16) * D_MODEL + k0 + k];
        }
        {   // B tile: 16 k x 64 cols
            const int k = tid >> 6, c = tid & 63;
            #pragma unroll
            for (int i = 0; i < 4; ++i)
                Bs[k + i*4][c] = W[(size_t)(k0 + k + i*4) * D_MODEL + col0 + c];
        }
        __syncthreads();
        #pragma unroll
        for (int kk = 0; kk < 16; ++kk) {
            float a[4], b[4];
            #pragma unroll
            for (int i = 0; i < 4; ++i) a[i] = As[kk][ty*4 + i];
            #pragma unroll
            for (int j = 0; j < 4; ++j) b[j] = Bs[kk][tx*4 + j];
            #pragma unroll
            for (int i = 0; i < 4; ++i)
                #pragma unroll
                for (int j = 0; j < 4; ++j)
                    acc[i][j] += a[i] * b[j];
        }
        __syncthreads();
    }

    // write out with [B,H,L,64] permutation
    #pragma unroll
    for (int i = 0; i < 4; ++i) {
        const int r = row0 + ty*4 + i;
        const int b = r >> 11, l = r & (SEQ - 1);
        #pragma unroll
        for (int j = 0; j < 4; ++j) {
            const int c = col0 + tx*4 + j;
            const int h = c >> 6, d = c & 63;
            out[(((size_t)b*NH + h)*SEQ + l)*64 + d] = __float2bfloat16(acc[i][j]);
        }
    }
}

// ---------------------------------------------------------------------------
// K2: banded attention. One 64-query tile per block; <=5 key tiles of 64.
// ctx layout: [B, L, H*64] bf16
// ---------------------------------------------------------------------------
__global__ __launch_bounds__(256)
void attn_kernel(const __hip_bfloat16* __restrict__ Qp,
                 const __hip_bfloat16* __restrict__ Kp,
                 const __hip_bfloat16* __restrict__ Vp,
                 __hip_bfloat16* __restrict__ ctx) {
    __shared__ float        Qs[64][65];
    __shared__ float        Ps[64][65];
    __shared__ __hip_bfloat16 Ks[64][72];
    __shared__ __hip_bfloat16 Vs[64][72];

    const int bh = blockIdx.y;            // 0..31
    const int b  = bh >> 3, h = bh & 7;
    const int q0 = blockIdx.x * 64;
    const int tid = threadIdx.x;
    const int tx = tid & 15, ty = tid >> 4;

    const size_t base = (size_t)bh * SEQ * 64;

    for (int e = tid; e < 64*64; e += 256) {
        const int r = e >> 6, d = e & 63;
        Qs[r][d] = __bfloat162float(Qp[base + (size_t)(q0 + r)*64 + d]);
    }

    float acc[4][4] = {};
    float rs[4] = {0.f, 0.f, 0.f, 0.f};

    int klo = q0 - (WINDOW - 1); if (klo < 0) klo = 0;
    const int kt0 = klo >> 6;
    const int kt1 = q0 >> 6;

    for (int kt = kt0; kt <= kt1; ++kt) {
        const int k0 = kt * 64;
        __syncthreads();   // previous PV done before overwriting Ks/Vs
        for (int e = tid; e < 64*64; e += 256) {
            const int r = e >> 6, d = e & 63;
            Ks[r][d] = Kp[base + (size_t)(k0 + r)*64 + d];
            Vs[r][d] = Vp[base + (size_t)(k0 + r)*64 + d];
        }
        __syncthreads();

        // scores: s[i][j] = Q[ty*4+i] . K[tx*4+j]
        float s[4][4] = {};
        #pragma unroll 8
        for (int d = 0; d < 64; ++d) {
            float a[4], kk[4];
            #pragma unroll
            for (int i = 0; i < 4; ++i) a[i] = Qs[ty*4 + i][d];
            #pragma unroll
            for (int j = 0; j < 4; ++j) kk[j] = __bfloat162float(Ks[tx*4 + j][d]);
            #pragma unroll
            for (int i = 0; i < 4; ++i)
                #pragma unroll
                for (int j = 0; j < 4; ++j)
                    s[i][j] += a[i] * kk[j];
        }

        // mask + exp -> Ps, accumulate row sums
        #pragma unroll
        for (int i = 0; i < 4; ++i) {
            const int gi = q0 + ty*4 + i;
            #pragma unroll
            for (int j = 0; j < 4; ++j) {
                const int gj = k0 + tx*4 + j;
                float p = 0.f;
                if (gj <= gi && gj + WINDOW > gi) p = __expf(s[i][j] * 0.125f);
                Ps[ty*4 + i][tx*4 + j] = p;
                rs[i] += p;
            }
        }
        __syncthreads();

        // PV: acc[i][jj] += sum_j Ps[row][j] * Vs[j][tx*4+jj]
        #pragma unroll 8
        for (int j = 0; j < 64; ++j) {
            float pv[4], vv[4];
            #pragma unroll
            for (int i = 0; i < 4; ++i) pv[i] = Ps[ty*4 + i][j];
            #pragma unroll
            for (int jj = 0; jj < 4; ++jj) vv[jj] = __bfloat162float(Vs[j][tx*4 + jj]);
            #pragma unroll
            for (int i = 0; i < 4; ++i)
                #pragma unroll
                for (int jj = 0; jj < 4; ++jj)
                    acc[i][jj] += pv[i] * vv[jj];
        }
    }

    // reduce row sums across the 16 lanes (tx) sharing each row group
    #pragma unroll
    for (int m = 1; m < 16; m <<= 1)
        #pragma unroll
        for (int i = 0; i < 4; ++i)
            rs[i] += __shfl_xor(rs[i], m, 64);

    #pragma unroll
    for (int i = 0; i < 4; ++i) {
        const int gi = q0 + ty*4 + i;
        const float inv = 1.0f / rs[i];
        #pragma unroll
        for (int j = 0; j < 4; ++j) {
            ctx[((size_t)b*SEQ + gi)*D_MODEL + h*64 + tx*4 + j] =
                __float2bfloat16(acc[i][j] * inv);
        }
    }
}

// ---------------------------------------------------------------------------
// K3: out = ctx(bf16) @ W_fc(f32) + input_Q  (fp32 out)
// ---------------------------------------------------------------------------
__global__ __launch_bounds__(256)
void fc_gemm(const __hip_bfloat16* __restrict__ ctx, const float* __restrict__ W,
             const float* __restrict__ resid, float* __restrict__ out) {
    __shared__ float As[16][65];
    __shared__ float Bs[16][65];

    const int tid = threadIdx.x;
    const int tx = tid & 15, ty = tid >> 4;
    const int row0 = blockIdx.x * 64;
    const int col0 = blockIdx.y * 64;

    float acc[4][4] = {};

    for (int k0 = 0; k0 < D_MODEL; k0 += 16) {
        {
            const int r = tid >> 4, k = tid & 15;
            #pragma unroll
            for (int i = 0; i < 4; ++i)
                As[k][r + i*16] =
                    __bfloat162float(ctx[(size_t)(row0 + r + i*16) * D_MODEL + k0 + k]);
        }
        {
            const int k = tid >> 6, c = tid & 63;
            #pragma unroll
            for (int i = 0; i < 4; ++i)
                Bs[k + i*4][c] = W[(size_t)(k0 + k + i*4) * D_MODEL + col0 + c];
        }
        __syncthreads();
        #pragma unroll
        for (int kk = 0; kk < 16; ++kk) {
            float a[4], b[4];
            #pragma unroll
            for (int i = 0; i < 4; ++i) a[i] = As[kk][ty*4 + i];
            #pragma unroll
            for (int j = 0; j < 4; ++j) b[j] = Bs[kk][tx*4 + j];
            #pragma unroll
            for (int i = 0; i < 4; ++i)
                #pragma unroll
                for (int j = 0; j < 4; ++j)
                    acc[i][j] += a[i] * b[j];
        }
        __syncthreads();
    }

    #pragma unroll
    for (int i = 0; i < 4; ++i) {
        const int r = row0 + ty*4 + i;
        #pragma unroll
        for (int j = 0; j < 4; ++j) {
            const int c = col0 + tx*4 + j;
            out[(size_t)r * D_MODEL + c] = acc[i][j] + resid[(size_t)r * D_MODEL + c];
        }
    }
}

// ---------------------------------------------------------------------------
// K4: in-place LayerNorm over last dim (512), one block per row
// ---------------------------------------------------------------------------
__global__ __launch_bounds__(256)
void ln_kernel(float* __restrict__ out) {
    const int row = blockIdx.x;
    float* p = out + (size_t)row * D_MODEL;
    const int tid = threadIdx.x;

    const float x0 = p[tid], x1 = p[tid + 256];
    float s  = x0 + x1;
    float s2 = x0*x0 + x1*x1;
    #pragma unroll
    for (int m = 1; m < 64; m <<= 1) {
        s  += __shfl_xor(s,  m, 64);
        s2 += __shfl_xor(s2, m, 64);
    }
    __shared__ float sa[4], sb[4];
    const int w = tid >> 6;
    if ((tid & 63) == 0) { sa[w] = s; sb[w] = s2; }
    __syncthreads();
    s  = sa[0] + sa[1] + sa[2] + sa[3];
    s2 = sb[0] + sb[1] + sb[2] + sb[3];

    const float mean = s * (1.0f / D_MODEL);
    const float var  = s2 * (1.0f / D_MODEL) - mean * mean;
    const float rstd = rsqrtf(var + 1e-5f);

    p[tid]       = (x0 - mean) * rstd;
    p[tid + 256] = (x1 - mean) * rstd;
}

// ---------------------------------------------------------------------------
extern "C" void kernel_launch(void* const* d_in, const int* in_sizes, int n_in,
                              void* d_out, int out_size, void* d_ws, size_t ws_size,
                              hipStream_t stream) {
    const float* inQ = (const float*)d_in[0];
    const float* inK = (const float*)d_in[1];
    const float* inV = (const float*)d_in[2];
    const float* WQ  = (const float*)d_in[3];
    const float* WK  = (const float*)d_in[4];
    const float* WV  = (const float*)d_in[5];
    const float* Wfc = (const float*)d_in[6];
    float* out = (float*)d_out;

    __hip_bfloat16* ws = (__hip_bfloat16*)d_ws;
    const size_t NE = (size_t)BATCH * NH * SEQ * 64;  // 4M elems
    __hip_bfloat16* Qp  = ws;
    __hip_bfloat16* Kp  = ws + NE;
    __hip_bfloat16* Vp  = ws + 2*NE;
    __hip_bfloat16* ctx = ws + 3*NE;

    dim3 gg(ROWS/64, D_MODEL/64);   // 128 x 8
    dim3 bb(256);

    proj_gemm<<<gg, bb, 0, stream>>>(inQ, WQ, Qp);
    proj_gemm<<<gg, bb, 0, stream>>>(inK, WK, Kp);
    proj_gemm<<<gg, bb, 0, stream>>>(inV, WV, Vp);

    attn_kernel<<<dim3(SEQ/64, BATCH*NH), bb, 0, stream>>>(Qp, Kp, Vp, ctx);

    fc_gemm<<<gg, bb, 0, stream>>>(ctx, Wfc, inQ, out);

    ln_kernel<<<ROWS, bb, 0, stream>>>(out);
}

// Round 2
// 170.698 us; speedup vs baseline: 3.1938x; 3.1938x over previous
//
#include <hip/hip_runtime.h>
#include <hip/hip_bf16.h>

#define D_MODEL 512
#define NH      8
#define SEQ     2048
#define BATCH   4
#define WINDOW  256
#define ROWS    (BATCH*SEQ)   // 8192

typedef __attribute__((ext_vector_type(8))) short bf16x8;
typedef __attribute__((ext_vector_type(4))) float f32x4;
typedef __hip_bfloat16 bf16;

__device__ __forceinline__ f32x4 mfma16(bf16x8 a, bf16x8 b, f32x4 c) {
    return __builtin_amdgcn_mfma_f32_16x16x32_bf16(a, b, c, 0, 0, 0);
}

__device__ __forceinline__ void gload16(const void* g, void* l) {
    __builtin_amdgcn_global_load_lds((const __attribute__((address_space(1))) void*)g,
                                     (__attribute__((address_space(3))) void*)l, 16, 0, 0);
}

__device__ __forceinline__ unsigned f2bf_u(float f) {
    bf16 h = __float2bfloat16(f);
    return (unsigned)(*(unsigned short*)&h);
}

// ---------------------------------------------------------------------------
// W transpose+convert: W[512k][512n] f32 -> Wt[512n][512k] bf16 (4 weights via z)
// ---------------------------------------------------------------------------
__global__ __launch_bounds__(256)
void wconv(const float* __restrict__ W0, const float* __restrict__ W1,
           const float* __restrict__ W2, const float* __restrict__ W3,
           bf16* __restrict__ Wt) {
    const int z = blockIdx.z;
    const float* W = (z == 0) ? W0 : (z == 1) ? W1 : (z == 2) ? W2 : W3;
    bf16* dst = Wt + (size_t)z * D_MODEL * D_MODEL;

    __shared__ float t[64][65];
    const int k0 = blockIdx.x * 64, n0 = blockIdx.y * 64;
    const int tid = threadIdx.x;

    #pragma unroll
    for (int i = 0; i < 16; ++i) {
        const int e = tid + 256 * i, r = e >> 6, c = e & 63;
        t[r][c] = W[(size_t)(k0 + r) * D_MODEL + n0 + c];
    }
    __syncthreads();
    #pragma unroll
    for (int i = 0; i < 16; ++i) {
        const int e = tid + 256 * i, r = e >> 6, c = e & 63;
        dst[(size_t)(n0 + r) * D_MODEL + k0 + c] = __float2bfloat16(t[c][r]);
    }
}

// ---------------------------------------------------------------------------
// Projection GEMM (MFMA): X[8192x512] f32 @ Wt^T -> Q/K: [B,H,L,64] bf16,
// V (z==2): [B,H,64,L] bf16 (transposed for attention B-operand)
// 128x128 tile, BK=64, 4 waves (2x2), XOR-swizzled LDS.
// ---------------------------------------------------------------------------
__global__ __launch_bounds__(256)
void proj_mfma(const float* __restrict__ Xq, const float* __restrict__ Xk,
               const float* __restrict__ Xv, const bf16* __restrict__ Wt,
               bf16* __restrict__ Qp, bf16* __restrict__ Kp, bf16* __restrict__ Vp) {
    const int z = blockIdx.z;
    const float* X = (z == 0) ? Xq : (z == 1) ? Xk : Xv;
    const bf16* W = Wt + (size_t)z * D_MODEL * D_MODEL;   // [n][k] bf16
    bf16* outp = (z == 0) ? Qp : (z == 1) ? Kp : Vp;

    __shared__ bf16 Asw[128 * 64];
    __shared__ bf16 Bsw[128 * 64];

    const int tid = threadIdx.x;
    const int lane = tid & 63, w = tid >> 6;
    const int wr = w >> 1, wc = w & 1;
    const int row0 = blockIdx.x * 128, col0 = blockIdx.y * 128;
    const int g = lane >> 4, m16 = lane & 15;

    f32x4 acc[4][4] = {};

    for (int step = 0; step < 8; ++step) {
        const int k0 = step * 64;
        __syncthreads();
        // B: global_load_lds, pre-swizzled source
        #pragma unroll
        for (int i = 0; i < 4; ++i) {
            const int chunk = i * 256 + w * 64 + lane;
            const int n = chunk >> 3, s = chunk & 7;
            gload16(W + (size_t)(col0 + n) * D_MODEL + k0 + ((s ^ (n & 7)) * 8),
                    &Bsw[(size_t)(i * 256 + w * 64) * 8]);
        }
        // A: reg-staged f32 -> bf16, swizzled source offset, linear LDS write
        #pragma unroll
        for (int i = 0; i < 4; ++i) {
            const int chunk = i * 256 + tid;
            const int m = chunk >> 3, s = chunk & 7;
            const float* gp = X + (size_t)(row0 + m) * D_MODEL + k0 + ((s ^ (m & 7)) * 8);
            const float4 f0 = *(const float4*)gp;
            const float4 f1 = *(const float4*)(gp + 4);
            int4 pk;
            pk.x = f2bf_u(f0.x) | (f2bf_u(f0.y) << 16);
            pk.y = f2bf_u(f0.z) | (f2bf_u(f0.w) << 16);
            pk.z = f2bf_u(f1.x) | (f2bf_u(f1.y) << 16);
            pk.w = f2bf_u(f1.z) | (f2bf_u(f1.w) << 16);
            *(int4*)&Asw[m * 64 + s * 8] = pk;
        }
        __syncthreads();

        #pragma unroll
        for (int c = 0; c < 2; ++c) {
            bf16x8 af[4], bfr[4];
            #pragma unroll
            for (int mi = 0; mi < 4; ++mi) {
                const int m = wr * 64 + mi * 16 + m16;
                const int slot = (c * 4 + g) ^ (m & 7);
                af[mi] = *(const bf16x8*)&Asw[m * 64 + slot * 8];
            }
            #pragma unroll
            for (int ni = 0; ni < 4; ++ni) {
                const int n = wc * 64 + ni * 16 + m16;
                const int slot = (c * 4 + g) ^ (n & 7);
                bfr[ni] = *(const bf16x8*)&Bsw[n * 64 + slot * 8];
            }
            #pragma unroll
            for (int mi = 0; mi < 4; ++mi)
                #pragma unroll
                for (int ni = 0; ni < 4; ++ni)
                    acc[mi][ni] = mfma16(af[mi], bfr[ni], acc[mi][ni]);
        }
    }

    if (z < 2) {
        // [B,H,L,64]
        #pragma unroll
        for (int mi = 0; mi < 4; ++mi)
            #pragma unroll
            for (int ni = 0; ni < 4; ++ni) {
                const int c = col0 + wc * 64 + ni * 16 + m16;
                const int h = c >> 6, d = c & 63;
                #pragma unroll
                for (int reg = 0; reg < 4; ++reg) {
                    const int r = row0 + wr * 64 + mi * 16 + g * 4 + reg;
                    const int b = r >> 11, l = r & (SEQ - 1);
                    outp[(((size_t)b * NH + h) * SEQ + l) * 64 + d] =
                        __float2bfloat16(acc[mi][ni][reg]);
                }
            }
    } else {
        // V transposed: [B,H,64,SEQ]; 4 consecutive rows (l) pack to 8B
        #pragma unroll
        for (int mi = 0; mi < 4; ++mi)
            #pragma unroll
            for (int ni = 0; ni < 4; ++ni) {
                const int c = col0 + wc * 64 + ni * 16 + m16;
                const int h = c >> 6, d = c & 63;
                const int r = row0 + wr * 64 + mi * 16 + g * 4;
                const int b = r >> 11, l = r & (SEQ - 1);
                uint2 pv;
                pv.x = f2bf_u(acc[mi][ni][0]) | (f2bf_u(acc[mi][ni][1]) << 16);
                pv.y = f2bf_u(acc[mi][ni][2]) | (f2bf_u(acc[mi][ni][3]) << 16);
                *(uint2*)&outp[(((size_t)b * NH + h) * 64 + d) * SEQ + l] = pv;
            }
    }
}

// ---------------------------------------------------------------------------
// Banded flash attention (MFMA). 4 waves x 16 q-rows, 64-key tiles.
// S^T = mfma(K, Q); softmax (no max-sub); P -> LDS bf16; O = mfma(P, V^T).
// ---------------------------------------------------------------------------
__global__ __launch_bounds__(256)
void attn_mfma(const bf16* __restrict__ Qp, const bf16* __restrict__ Kp,
               const bf16* __restrict__ Vp, bf16* __restrict__ ctx) {
    __shared__ bf16 Qs[64][72];
    __shared__ bf16 Ks[64][72];
    __shared__ bf16 Vt[64][72];
    __shared__ bf16 Ps[4][16][72];

    const int bh = blockIdx.y, b = bh >> 3, h = bh & 7;
    const int q0 = blockIdx.x * 64;
    const int tid = threadIdx.x;
    const int lane = tid & 63, w = tid >> 6;
    const int g = lane >> 4, m16 = lane & 15;

    const size_t kvbase = (size_t)bh * SEQ * 64;   // Qp/Kp [bh][l][64]
    const size_t vtbase = (size_t)bh * 64 * SEQ;   // Vp    [bh][d][l]

    // stage Q (64x64)
    #pragma unroll
    for (int i = 0; i < 2; ++i) {
        const int chunk = i * 256 + tid, r = chunk >> 3, s = chunk & 7;
        *(int4*)&Qs[r][s * 8] = *(const int4*)(Qp + kvbase + (size_t)(q0 + r) * 64 + s * 8);
    }
    __syncthreads();

    // hoisted Q fragments (B operand)
    bf16x8 qf[2];
    #pragma unroll
    for (int c = 0; c < 2; ++c)
        qf[c] = *(const bf16x8*)&Qs[w * 16 + m16][c * 32 + g * 8];

    f32x4 o[4] = {};
    float rs = 0.f;

    int klo = q0 - (WINDOW - 1); if (klo < 0) klo = 0;
    const int kt0 = klo >> 6, kt1 = q0 >> 6;
    const int qg = q0 + w * 16 + m16;

    for (int kt = kt0; kt <= kt1; ++kt) {
        const int k0 = kt * 64;
        __syncthreads();
        #pragma unroll
        for (int i = 0; i < 2; ++i) {
            const int chunk = i * 256 + tid, r = chunk >> 3, s = chunk & 7;
            *(int4*)&Ks[r][s * 8] = *(const int4*)(Kp + kvbase + (size_t)(k0 + r) * 64 + s * 8);
            *(int4*)&Vt[r][s * 8] = *(const int4*)(Vp + vtbase + (size_t)r * SEQ + k0 + s * 8);
        }
        __syncthreads();

        // S^T[f] = K_f . Q^T  (64 keys x 16 queries)
        f32x4 st[4] = {};
        #pragma unroll
        for (int c = 0; c < 2; ++c) {
            bf16x8 kf[4];
            #pragma unroll
            for (int f = 0; f < 4; ++f)
                kf[f] = *(const bf16x8*)&Ks[f * 16 + m16][c * 32 + g * 8];
            #pragma unroll
            for (int f = 0; f < 4; ++f)
                st[f] = mfma16(kf[f], qf[c], st[f]);
        }

        // mask + exp + rowsum; pack P to LDS (per-wave region)
        const int masktype = (k0 == q0) ? 1 : ((k0 < q0 - 192) ? 2 : 0);
        #pragma unroll
        for (int f = 0; f < 4; ++f) {
            float p[4];
            #pragma unroll
            for (int reg = 0; reg < 4; ++reg) {
                const int kg = k0 + f * 16 + g * 4 + reg;
                bool valid = (masktype == 0) || (masktype == 1 ? (kg <= qg)
                                                              : (kg >= qg - (WINDOW - 1)));
                p[reg] = valid ? __expf(st[f][reg] * 0.125f) : 0.f;
                rs += p[reg];
            }
            uint2 pkv;
            pkv.x = f2bf_u(p[0]) | (f2bf_u(p[1]) << 16);
            pkv.y = f2bf_u(p[2]) | (f2bf_u(p[3]) << 16);
            *(uint2*)&Ps[w][m16][f * 16 + g * 4] = pkv;
        }

        // O += P . V^T
        #pragma unroll
        for (int c = 0; c < 2; ++c) {
            const bf16x8 pf = *(const bf16x8*)&Ps[w][m16][c * 32 + g * 8];
            #pragma unroll
            for (int f2 = 0; f2 < 4; ++f2) {
                const bf16x8 vf = *(const bf16x8*)&Vt[f2 * 16 + m16][c * 32 + g * 8];
                o[f2] = mfma16(pf, vf, o[f2]);
            }
        }
    }

    // denominators: full sum for q = lane&15 after xor-16/32
    rs += __shfl_xor(rs, 16, 64);
    rs += __shfl_xor(rs, 32, 64);
    const float inv = 1.0f / rs;
    float invr[4];
    #pragma unroll
    for (int reg = 0; reg < 4; ++reg)
        invr[reg] = __shfl(inv, g * 4 + reg, 64);

    #pragma unroll
    for (int f2 = 0; f2 < 4; ++f2) {
        const int d = f2 * 16 + m16;
        #pragma unroll
        for (int reg = 0; reg < 4; ++reg) {
            const int qrow = w * 16 + g * 4 + reg;
            ctx[((size_t)b * SEQ + q0 + qrow) * D_MODEL + h * 64 + d] =
                __float2bfloat16(o[f2][reg] * invr[reg]);
        }
    }
}

// ---------------------------------------------------------------------------
// fc GEMM (MFMA): ctx[8192x512] bf16 @ Wfc^T + resid -> out f32
// ---------------------------------------------------------------------------
__global__ __launch_bounds__(256)
void fc_mfma(const bf16* __restrict__ ctx, const bf16* __restrict__ Wt,
             const float* __restrict__ resid, float* __restrict__ out) {
    __shared__ bf16 Asw[128 * 64];
    __shared__ bf16 Bsw[128 * 64];

    const int tid = threadIdx.x;
    const int lane = tid & 63, w = tid >> 6;
    const int wr = w >> 1, wc = w & 1;
    const int row0 = blockIdx.x * 128, col0 = blockIdx.y * 128;
    const int g = lane >> 4, m16 = lane & 15;

    f32x4 acc[4][4] = {};

    for (int step = 0; step < 8; ++step) {
        const int k0 = step * 64;
        __syncthreads();
        #pragma unroll
        for (int i = 0; i < 4; ++i) {
            const int chunk = i * 256 + w * 64 + lane;
            const int m = chunk >> 3, s = chunk & 7;
            gload16(ctx + (size_t)(row0 + m) * D_MODEL + k0 + ((s ^ (m & 7)) * 8),
                    &Asw[(size_t)(i * 256 + w * 64) * 8]);
            gload16(Wt + (size_t)(col0 + m) * D_MODEL + k0 + ((s ^ (m & 7)) * 8),
                    &Bsw[(size_t)(i * 256 + w * 64) * 8]);
        }
        __syncthreads();

        #pragma unroll
        for (int c = 0; c < 2; ++c) {
            bf16x8 af[4], bfr[4];
            #pragma unroll
            for (int mi = 0; mi < 4; ++mi) {
                const int m = wr * 64 + mi * 16 + m16;
                const int slot = (c * 4 + g) ^ (m & 7);
                af[mi] = *(const bf16x8*)&Asw[m * 64 + slot * 8];
            }
            #pragma unroll
            for (int ni = 0; ni < 4; ++ni) {
                const int n = wc * 64 + ni * 16 + m16;
                const int slot = (c * 4 + g) ^ (n & 7);
                bfr[ni] = *(const bf16x8*)&Bsw[n * 64 + slot * 8];
            }
            #pragma unroll
            for (int mi = 0; mi < 4; ++mi)
                #pragma unroll
                for (int ni = 0; ni < 4; ++ni)
                    acc[mi][ni] = mfma16(af[mi], bfr[ni], acc[mi][ni]);
        }
    }

    #pragma unroll
    for (int mi = 0; mi < 4; ++mi)
        #pragma unroll
        for (int ni = 0; ni < 4; ++ni) {
            const int c = col0 + wc * 64 + ni * 16 + m16;
            #pragma unroll
            for (int reg = 0; reg < 4; ++reg) {
                const int r = row0 + wr * 64 + mi * 16 + g * 4 + reg;
                out[(size_t)r * D_MODEL + c] = acc[mi][ni][reg] + resid[(size_t)r * D_MODEL + c];
            }
        }
}

// ---------------------------------------------------------------------------
// LayerNorm in-place over last dim (512)
// ---------------------------------------------------------------------------
__global__ __launch_bounds__(256)
void ln_kernel(float* __restrict__ out) {
    const int row = blockIdx.x;
    float* p = out + (size_t)row * D_MODEL;
    const int tid = threadIdx.x;

    const float x0 = p[tid], x1 = p[tid + 256];
    float s  = x0 + x1;
    float s2 = x0 * x0 + x1 * x1;
    #pragma unroll
    for (int m = 1; m < 64; m <<= 1) {
        s  += __shfl_xor(s,  m, 64);
        s2 += __shfl_xor(s2, m, 64);
    }
    __shared__ float sa[4], sb[4];
    const int w = tid >> 6;
    if ((tid & 63) == 0) { sa[w] = s; sb[w] = s2; }
    __syncthreads();
    s  = sa[0] + sa[1] + sa[2] + sa[3];
    s2 = sb[0] + sb[1] + sb[2] + sb[3];

    const float mean = s * (1.0f / D_MODEL);
    const float var  = s2 * (1.0f / D_MODEL) - mean * mean;
    const float rstd = rsqrtf(var + 1e-5f);

    p[tid]       = (x0 - mean) * rstd;
    p[tid + 256] = (x1 - mean) * rstd;
}

// ---------------------------------------------------------------------------
extern "C" void kernel_launch(void* const* d_in, const int* in_sizes, int n_in,
                              void* d_out, int out_size, void* d_ws, size_t ws_size,
                              hipStream_t stream) {
    const float* inQ = (const float*)d_in[0];
    const float* inK = (const float*)d_in[1];
    const float* inV = (const float*)d_in[2];
    const float* WQ  = (const float*)d_in[3];
    const float* WK  = (const float*)d_in[4];
    const float* WV  = (const float*)d_in[5];
    const float* Wfc = (const float*)d_in[6];
    float* out = (float*)d_out;

    bf16* ws = (bf16*)d_ws;
    const size_t WSZ = (size_t)D_MODEL * D_MODEL;       // 262144
    const size_t NE  = (size_t)BATCH * NH * SEQ * 64;   // 4194304
    bf16* Wt   = ws;                 // 4 transposed bf16 weights
    bf16* Qp   = ws + 4 * WSZ;
    bf16* Kp   = Qp + NE;
    bf16* Vp   = Kp + NE;
    bf16* ctxb = Vp + NE;

    wconv<<<dim3(8, 8, 4), 256, 0, stream>>>(WQ, WK, WV, Wfc, Wt);
    proj_mfma<<<dim3(ROWS / 128, D_MODEL / 128, 3), 256, 0, stream>>>(
        inQ, inK, inV, Wt, Qp, Kp, Vp);
    attn_mfma<<<dim3(SEQ / 64, BATCH * NH), 256, 0, stream>>>(Qp, Kp, Vp, ctxb);
    fc_mfma<<<dim3(ROWS / 128, D_MODEL / 128), 256, 0, stream>>>(
        ctxb, Wt + 3 * WSZ, inQ, out);
    ln_kernel<<<ROWS, 256, 0, stream>>>(out);
}